// Round 8
// baseline (21.575 us; speedup 1.0000x reference)
//
#include <hip/hip_runtime.h>
#include <math.h>

// FundusQuantumLayer: 4-qubit, 3-layer variational circuit, batch 2^20.
// ev[q] = sum_{P in {I,Z,X}^4} C[q][P] * prod_r w_{P_r}(x_r), w = (1,cos x,sin x).
// Kernel 1 builds C (4x81) once; kernel 2 streams samples.
//
// Measured history:
//  R4: SPT=4, LDS table, no cap   -> 252 VGPR, 2 waves/SIMD, ~40us (latency)
//  R5/R6: launch_bounds caps 64/84 -> spill, 790MB scratch, 195/254us
//  R7: coefficients via AS4 s_load (SGPR-resident, 0 VGPR), SPT=1 -> 20.6us
// This round: SPT=2, dual-sample interleave inside each coefficient chunk
// (halves per-wave s_load/SMEM overhead, 2x ILP per s_waitcnt window).

typedef float f4 __attribute__((ext_vector_type(4)));
typedef const f4 __attribute__((address_space(4)))* c4ptr;  // constant AS -> s_load

#define SPT 2

__global__ void fq_setup(const float* __restrict__ w, float4* __restrict__ Ct) {
    __shared__ float2 sU[16][16];      // U[row][col] (re,im) of shared block
    __shared__ float  sReM[4][16][16]; // Re(U^dag Z_q U)
    const int tid = threadIdx.x;

    // ---- Stage A: simulate shared block; thread (r,c) holds U[r][c].
    {
        const int r = tid & 15, c = tid >> 4;
        float ar = (r == c) ? 1.f : 0.f, ai = 0.f;
#pragma unroll
        for (int l = 0; l < 3; ++l) {
#pragma unroll
            for (int q = 0; q < 4; ++q) {
                const int m = 1 << (3 - q);          // qubit 0 = MSB
                {   // RY(w[l][q][0])
                    float th = w[(l*4 + q)*2 + 0];
                    float cg = __cosf(0.5f*th), sg = __sinf(0.5f*th);
                    float obr = __shfl_xor(ar, m, 64);
                    float obi = __shfl_xor(ai, m, 64);
                    float t2 = (r & m) ? sg : -sg;
                    ar = cg*ar + t2*obr;
                    ai = cg*ai + t2*obi;
                }
                {   // RZ(w[l][q][1])
                    float ph = w[(l*4 + q)*2 + 1];
                    float cp = __cosf(0.5f*ph), sp = __sinf(0.5f*ph);
                    float t2 = (r & m) ? sp : -sp;
                    float nr = cp*ar - t2*ai;
                    float ni = cp*ai + t2*ar;
                    ar = nr; ai = ni;
                }
            }
            // CNOT ring (0,1),(1,2),(2,3),(3,0)
#pragma unroll
            for (int e = 0; e < 4; ++e) {
                const int mc = 1 << (3 - e);
                const int mt = 1 << (3 - ((e + 1) & 3));
                float obr = __shfl_xor(ar, mt, 64);
                float obi = __shfl_xor(ai, mt, 64);
                if (r & mc) { ar = obr; ai = obi; }
            }
        }
        sU[r][c] = make_float2(ar, ai);
    }
    __syncthreads();

    // ---- Stage B: ReM[q][i][j] = sum_k z_q(k) Re(conj(U[k][i]) U[k][j])
    {
        const int i = tid >> 4, j = tid & 15;
        float s0 = 0.f, s1 = 0.f, s2 = 0.f, s3 = 0.f;
#pragma unroll
        for (int k = 0; k < 16; ++k) {
            float2 uik = sU[k][i], ujk = sU[k][j];
            float pr = uik.x*ujk.x + uik.y*ujk.y;
            s0 += (k & 8) ? -pr : pr;
            s1 += (k & 4) ? -pr : pr;
            s2 += (k & 2) ? -pr : pr;
            s3 += (k & 1) ? -pr : pr;
        }
        sReM[0][i][j] = s0; sReM[1][i][j] = s1;
        sReM[2][i][j] = s2; sReM[3][i][j] = s3;
    }
    __syncthreads();

    // ---- Stage C: Ct[k81].q = tr(M_q P_{k81})/16, digits: 0=I 1=Z 2=X
    for (int idx = tid; idx < 324; idx += 256) {
        int q = idx / 81, k81 = idx % 81;
        int p0 = k81/27, p1 = (k81/9)%3, p2 = (k81/3)%3, p3 = k81%3;
        int xm = 0, zm = 0;
        if (p0 == 1) zm |= 8; else if (p0 == 2) xm |= 8;
        if (p1 == 1) zm |= 4; else if (p1 == 2) xm |= 4;
        if (p2 == 1) zm |= 2; else if (p2 == 2) xm |= 2;
        if (p3 == 1) zm |= 1; else if (p3 == 2) xm |= 1;
        float sum = 0.f;
#pragma unroll
        for (int j = 0; j < 16; ++j) {
            float sgn = (__popc(j & zm) & 1) ? -1.f : 1.f;
            sum += sgn * sReM[q][j ^ xm][j];
        }
        ((float*)Ct)[k81*4 + q] = sum * 0.0625f;
    }
}

__global__ __launch_bounds__(256) void fq_main(const float4* __restrict__ x,
                                               const float* __restrict__ Ct,
                                               float4* __restrict__ out) {
    const int t0 = blockIdx.x * 256 + threadIdx.x;
    const int NT = gridDim.x * 256;            // second sample at t0 + NT

    // Wave-uniform coefficient table via constant address space -> s_load,
    // coefficients live in SGPRs (zero VGPR cost).
    c4ptr C = (c4ptr)(unsigned long long)Ct;

    float g01[SPT][9], g23[SPT][9];
#pragma unroll
    for (int s = 0; s < SPT; ++s) {
        float4 xv = x[t0 + s*NT];
        float c0 = __cosf(xv.x), s0 = __sinf(xv.x);
        float c1 = __cosf(xv.y), s1 = __sinf(xv.y);
        float c2 = __cosf(xv.z), s2 = __sinf(xv.z);
        float c3 = __cosf(xv.w), s3 = __sinf(xv.w);
        float f0[3] = {1.f, c0, s0}, f1[3] = {1.f, c1, s1};
        float f2[3] = {1.f, c2, s2}, f3[3] = {1.f, c3, s3};
#pragma unroll
        for (int a = 0; a < 3; ++a)
#pragma unroll
            for (int b = 0; b < 3; ++b) {
                g01[s][a*3+b] = f0[a] * f1[b];   // *1.0f entries fold
                g23[s][a*3+b] = f2[a] * f3[b];
            }
    }

    float a0[SPT] = {0.f, 0.f}, a1[SPT] = {0.f, 0.f};
    float a2[SPT] = {0.f, 0.f}, a3[SPT] = {0.f, 0.f};
#pragma unroll
    for (int a = 0; a < 9; ++a) {
        float t0r[SPT] = {0.f, 0.f}, t1r[SPT] = {0.f, 0.f};
        float t2r[SPT] = {0.f, 0.f}, t3r[SPT] = {0.f, 0.f};
#pragma unroll
        for (int b = 0; b < 9; ++b) {
            f4 c = C[a*9 + b];                 // s_load_dwordx4 (uniform addr)
#pragma unroll
            for (int s = 0; s < SPT; ++s) {    // dual-sample ILP per chunk
                float g = g23[s][b];
                t0r[s] = fmaf(c[0], g, t0r[s]);
                t1r[s] = fmaf(c[1], g, t1r[s]);
                t2r[s] = fmaf(c[2], g, t2r[s]);
                t3r[s] = fmaf(c[3], g, t3r[s]);
            }
        }
#pragma unroll
        for (int s = 0; s < SPT; ++s) {
            float g = g01[s][a];
            a0[s] = fmaf(t0r[s], g, a0[s]);
            a1[s] = fmaf(t1r[s], g, a1[s]);
            a2[s] = fmaf(t2r[s], g, a2[s]);
            a3[s] = fmaf(t3r[s], g, a3[s]);
        }
    }

#pragma unroll
    for (int s = 0; s < SPT; ++s)
        out[t0 + s*NT] = make_float4(a0[s], a1[s], a2[s], a3[s]);
}

extern "C" void kernel_launch(void* const* d_in, const int* in_sizes, int n_in,
                              void* d_out, int out_size, void* d_ws, size_t ws_size,
                              hipStream_t stream) {
    const float* x = (const float*)d_in[0];     // [B,4] f32
    const float* w = (const float*)d_in[1];     // [3,4,2] f32
    float4* Ct = (float4*)d_ws;                 // 81 float4 scratch

    fq_setup<<<1, 256, 0, stream>>>(w, Ct);

    const int B = in_sizes[0] / 4;              // 1048576
    const int threads = B / SPT;                // 524288
    fq_main<<<threads / 256, 256, 0, stream>>>((const float4*)x, (const float*)Ct,
                                               (float4*)d_out);
}

// Round 9
// 20.246 us; speedup vs baseline: 1.0657x; 1.0657x over previous
//
#include <hip/hip_runtime.h>
#include <math.h>

// FundusQuantumLayer: 4-qubit, 3-layer variational circuit, batch 2^20.
// ev[q] = sum_{P in {I,Z,X}^4} C[q][P] * prod_r w_{P_r}(x_r), w = (1,cos x,sin x).
// Kernel 1 builds C (4x81) once; kernel 2 streams samples.
//
// Measured history:
//  R4: SPT=4, LDS table, no cap    -> 252 VGPR, 2 waves/SIMD, ~40us (latency)
//  R5/R6: launch_bounds caps 64/84 -> spill, 790MB scratch traffic, 195/254us
//  R7: AS4 s_load table (SGPR-resident), SPT=1, scalar fma -> 20.6us
//  R8: SPT=2 dual-sample interleave -> 21.6us (neutral: NOT SMEM-bound,
//      NOT per-wave-overhead-bound)
// This round: SPT=1 + q-packed accumulators via v_pk_fma_f32 (VOP3P packed
// fp32 = the only path to the 157 TF fp32 peak). {c[0],c[1]} are adjacent
// SGPRs from s_load_dwordx4 -> natural 64b packed scalar source. Core drops
// 360 scalar FMA -> 180 packed ops per sample.

typedef float f4 __attribute__((ext_vector_type(4)));
typedef float f2 __attribute__((ext_vector_type(2)));
typedef const f4 __attribute__((address_space(4)))* c4ptr;  // constant AS -> s_load

__global__ void fq_setup(const float* __restrict__ w, float4* __restrict__ Ct) {
    __shared__ float2 sU[16][16];      // U[row][col] (re,im) of shared block
    __shared__ float  sReM[4][16][16]; // Re(U^dag Z_q U)
    const int tid = threadIdx.x;

    // ---- Stage A: simulate shared block; thread (r,c) holds U[r][c].
    {
        const int r = tid & 15, c = tid >> 4;
        float ar = (r == c) ? 1.f : 0.f, ai = 0.f;
#pragma unroll
        for (int l = 0; l < 3; ++l) {
#pragma unroll
            for (int q = 0; q < 4; ++q) {
                const int m = 1 << (3 - q);          // qubit 0 = MSB
                {   // RY(w[l][q][0])
                    float th = w[(l*4 + q)*2 + 0];
                    float cg = __cosf(0.5f*th), sg = __sinf(0.5f*th);
                    float obr = __shfl_xor(ar, m, 64);
                    float obi = __shfl_xor(ai, m, 64);
                    float t2 = (r & m) ? sg : -sg;
                    ar = cg*ar + t2*obr;
                    ai = cg*ai + t2*obi;
                }
                {   // RZ(w[l][q][1])
                    float ph = w[(l*4 + q)*2 + 1];
                    float cp = __cosf(0.5f*ph), sp = __sinf(0.5f*ph);
                    float t2 = (r & m) ? sp : -sp;
                    float nr = cp*ar - t2*ai;
                    float ni = cp*ai + t2*ar;
                    ar = nr; ai = ni;
                }
            }
            // CNOT ring (0,1),(1,2),(2,3),(3,0)
#pragma unroll
            for (int e = 0; e < 4; ++e) {
                const int mc = 1 << (3 - e);
                const int mt = 1 << (3 - ((e + 1) & 3));
                float obr = __shfl_xor(ar, mt, 64);
                float obi = __shfl_xor(ai, mt, 64);
                if (r & mc) { ar = obr; ai = obi; }
            }
        }
        sU[r][c] = make_float2(ar, ai);
    }
    __syncthreads();

    // ---- Stage B: ReM[q][i][j] = sum_k z_q(k) Re(conj(U[k][i]) U[k][j])
    {
        const int i = tid >> 4, j = tid & 15;
        float s0 = 0.f, s1 = 0.f, s2 = 0.f, s3 = 0.f;
#pragma unroll
        for (int k = 0; k < 16; ++k) {
            float2 uik = sU[k][i], ujk = sU[k][j];
            float pr = uik.x*ujk.x + uik.y*ujk.y;
            s0 += (k & 8) ? -pr : pr;
            s1 += (k & 4) ? -pr : pr;
            s2 += (k & 2) ? -pr : pr;
            s3 += (k & 1) ? -pr : pr;
        }
        sReM[0][i][j] = s0; sReM[1][i][j] = s1;
        sReM[2][i][j] = s2; sReM[3][i][j] = s3;
    }
    __syncthreads();

    // ---- Stage C: Ct[k81].q = tr(M_q P_{k81})/16, digits: 0=I 1=Z 2=X
    for (int idx = tid; idx < 324; idx += 256) {
        int q = idx / 81, k81 = idx % 81;
        int p0 = k81/27, p1 = (k81/9)%3, p2 = (k81/3)%3, p3 = k81%3;
        int xm = 0, zm = 0;
        if (p0 == 1) zm |= 8; else if (p0 == 2) xm |= 8;
        if (p1 == 1) zm |= 4; else if (p1 == 2) xm |= 4;
        if (p2 == 1) zm |= 2; else if (p2 == 2) xm |= 2;
        if (p3 == 1) zm |= 1; else if (p3 == 2) xm |= 1;
        float sum = 0.f;
#pragma unroll
        for (int j = 0; j < 16; ++j) {
            float sgn = (__popc(j & zm) & 1) ? -1.f : 1.f;
            sum += sgn * sReM[q][j ^ xm][j];
        }
        ((float*)Ct)[k81*4 + q] = sum * 0.0625f;
    }
}

__global__ __launch_bounds__(256) void fq_main(const float4* __restrict__ x,
                                               const float* __restrict__ Ct,
                                               float4* __restrict__ out) {
    const int i = blockIdx.x * 256 + threadIdx.x;

    // Wave-uniform coefficient table via constant address space -> s_load,
    // coefficients live in SGPRs (zero VGPR cost).
    c4ptr C = (c4ptr)(unsigned long long)Ct;

    float4 xv = x[i];
    float c0 = __cosf(xv.x), s0 = __sinf(xv.x);
    float c1 = __cosf(xv.y), s1 = __sinf(xv.y);
    float c2 = __cosf(xv.z), s2 = __sinf(xv.z);
    float c3 = __cosf(xv.w), s3 = __sinf(xv.w);

    float f0[3] = {1.f, c0, s0}, f1[3] = {1.f, c1, s1};
    float f2v[3] = {1.f, c2, s2}, f3[3] = {1.f, c3, s3};
    float g01[9], g23[9];
#pragma unroll
    for (int a = 0; a < 3; ++a)
#pragma unroll
        for (int b = 0; b < 3; ++b) {
            g01[a*3+b] = f0[a] * f1[b];        // *1.0f entries fold
            g23[a*3+b] = f2v[a] * f3[b];
        }

    // q-packed accumulators: (q0,q1) and (q2,q3) pairs -> v_pk_fma_f32.
    f2 a01 = {0.f, 0.f}, a23 = {0.f, 0.f};
#pragma unroll
    for (int a = 0; a < 9; ++a) {
        f2 t01 = {0.f, 0.f}, t23 = {0.f, 0.f};
#pragma unroll
        for (int b = 0; b < 9; ++b) {
            f4 c = C[a*9 + b];                 // s_load_dwordx4 (uniform addr)
            f2 c01 = {c[0], c[1]};             // adjacent SGPRs: natural 64b pair
            f2 c23 = {c[2], c[3]};
            float g = g23[b];
            f2 gg = {g, g};                    // opsel broadcast of one VGPR
            t01 = __builtin_elementwise_fma(c01, gg, t01);
            t23 = __builtin_elementwise_fma(c23, gg, t23);
        }
        float g = g01[a];
        f2 gg = {g, g};
        a01 = __builtin_elementwise_fma(t01, gg, a01);
        a23 = __builtin_elementwise_fma(t23, gg, a23);
    }

    out[i] = make_float4(a01.x, a01.y, a23.x, a23.y);
}

extern "C" void kernel_launch(void* const* d_in, const int* in_sizes, int n_in,
                              void* d_out, int out_size, void* d_ws, size_t ws_size,
                              hipStream_t stream) {
    const float* x = (const float*)d_in[0];     // [B,4] f32
    const float* w = (const float*)d_in[1];     // [3,4,2] f32
    float4* Ct = (float4*)d_ws;                 // 81 float4 scratch

    fq_setup<<<1, 256, 0, stream>>>(w, Ct);

    const int B = in_sizes[0] / 4;              // 1048576
    fq_main<<<B / 256, 256, 0, stream>>>((const float4*)x, (const float*)Ct,
                                         (float4*)d_out);
}